// Round 3
// baseline (1180.125 us; speedup 1.0000x reference)
//
#include <hip/hip_runtime.h>
#include <math.h>

// TopExpertsRouter on MI355X (gfx950) — two-phase, bit-identical to the
// PASSING round-1 numerics (chunked-512 sequential fmaf chains, chunks summed
// in order, identical softmax/top-k), with round-1's perf bugs fixed:
//
// Phase 1 (router_gemm): thread = token, acc[64] in VGPRs. Round 1 collapsed
// to VGPR=40 (compiler occupancy heuristic restructured acc[64] into
// x-rereads -> 615us). Fixes: __launch_bounds__(256,3) caps occupancy target
// so the allocator keeps ~110 VGPRs live; x staged in 8 float4 REGISTERS per
// 32-wide d-block so the unrolled e-loop re-reads x for free; W addresses are
// wave-uniform -> scalar s_loads, inner loop is chained v_fmac_f32.
// Per (token,expert,chunk): acc = fmaf chain over d sequential — bit-equal to
// round 1. Partials [chunk][expert][token], coalesced stores.
//
// Phase 2 (router_finish): block = 64 tokens, 256 threads. 4 expert-groups x
// 64 lanes reduce the 8 chunks with fully coalesced loads (c ascending —
// bit-equal to round 1's l[e] += p[c]) into LDS, then threads 0..63 run the
// byte-identical round-1 softmax/top-8 epilogue.

constexpr int D  = 4096;
constexpr int E  = 64;
constexpr int K  = 8;
constexpr int DB = 32;   // d-block held in registers (8 float4)

__global__ __launch_bounds__(256, 3) void router_gemm(
    const float* __restrict__ x, const float* __restrict__ W,
    float* __restrict__ partial, int ntok, int dlen, int ntiles)
{
    const int tile  = blockIdx.x % ntiles;
    const int chunk = blockIdx.x / ntiles;
    const int n  = tile * 256 + threadIdx.x;
    const int d0 = chunk * dlen;

    float acc[E];
#pragma unroll
    for (int e = 0; e < E; ++e) acc[e] = 0.f;

    const float* xp = x + (size_t)n * D + d0;

    for (int db = 0; db < dlen; db += DB) {
        // x d-block -> registers (8 float4); e-loop below re-reads them free
        float4 xr[DB / 4];
#pragma unroll
        for (int q = 0; q < DB / 4; ++q)
            xr[q] = *(const float4*)(xp + db + 4 * q);

        const float* wp0 = W + d0 + db;   // wave-uniform base
#pragma unroll
        for (int e = 0; e < E; ++e) {
            const float* wp = wp0 + (size_t)e * D;   // uniform -> s_load
            float a = acc[e];
#pragma unroll
            for (int q = 0; q < DB / 4; ++q) {
                const float4 wv = *(const float4*)(wp + 4 * q);
                const float4 xv = xr[q];
                a = fmaf(xv.x, wv.x, a);
                a = fmaf(xv.y, wv.y, a);
                a = fmaf(xv.z, wv.z, a);
                a = fmaf(xv.w, wv.w, a);
            }
            acc[e] = a;
        }
    }

    float* op = partial + (size_t)chunk * E * ntok + n;
#pragma unroll
    for (int e = 0; e < E; ++e) op[(size_t)e * ntok] = acc[e];  // coalesced
}

__global__ __launch_bounds__(256) void router_finish(
    const float* __restrict__ partial, float* __restrict__ out,
    int ntok, int nchunks)
{
    __shared__ float ls[64][E + 4];   // stride 68: 16B-aligned rows

    const int tid = threadIdx.x;
    const int t0  = blockIdx.x * 64;
    const int t   = tid & 63;         // token lane (coalesced dim)
    const int eg  = tid >> 6;         // expert group 0..3

#pragma unroll
    for (int j = 0; j < 16; ++j) {
        const int e = eg * 16 + j;
        const float* p = partial + (size_t)e * ntok + t0 + t;
        float v = p[0];                              // chunk 0
        for (int c = 1; c < nchunks; ++c)            // ascending: bit-equal
            v += p[(size_t)c * E * ntok];            // to round-1 reduction
        ls[t][e] = v;
    }
    __syncthreads();

    if (tid < 64) {
        const int n = t0 + tid;
        float l[E];
#pragma unroll
        for (int g = 0; g < 16; ++g) {
            const float4 v = *(const float4*)&ls[tid][g * 4];
            l[g * 4 + 0] = v.x; l[g * 4 + 1] = v.y;
            l[g * 4 + 2] = v.z; l[g * 4 + 3] = v.w;
        }

        // ---- identical to round-1 epilogue ----
        float m = l[0];
#pragma unroll
        for (int e = 1; e < E; ++e) m = fmaxf(m, l[e]);
        float sum = 0.f;
#pragma unroll
        for (int e = 0; e < E; ++e) { l[e] = expf(l[e] - m); sum += l[e]; }
        const float inv = 1.f / sum;
#pragma unroll
        for (int e = 0; e < E; ++e) l[e] *= inv;

        float* probs = out + (size_t)ntok * 2 * K + (size_t)n * E;
#pragma unroll
        for (int g = 0; g < 16; ++g)
            *(float4*)&probs[g * 4] =
                make_float4(l[g * 4], l[g * 4 + 1], l[g * 4 + 2], l[g * 4 + 3]);

        float vals[K];
        int   idxs[K];
        float ts = 0.f;
        for (int k = 0; k < K; ++k) {
            float best = -1.f;
            int   bi   = 0;
#pragma unroll
            for (int e = 0; e < E; ++e)
                if (l[e] > best) { best = l[e]; bi = e; }
            vals[k] = best;
            idxs[k] = bi;
            ts += best;
#pragma unroll
            for (int e = 0; e < E; ++e)
                if (e == bi) l[e] = -1.f;
        }
        const float winv = 1.f / (ts + 1e-9f);

        float* oi = out + (size_t)n * K;
        float* ow = out + (size_t)ntok * K + (size_t)n * K;
#pragma unroll
        for (int k = 0; k < K; ++k) {
            oi[k] = (float)idxs[k];
            ow[k] = vals[k] * winv;
        }
    }
}

extern "C" void kernel_launch(void* const* d_in, const int* in_sizes, int n_in,
                              void* d_out, int out_size, void* d_ws, size_t ws_size,
                              hipStream_t stream)
{
    const float* x = (const float*)d_in[0];
    const float* W = (const float*)d_in[1];
    float* out = (float*)d_out;

    const int ntok = in_sizes[0] / D;  // 16384

    // identical nchunks policy to round 1 (bit-exactness anchor)
    int nchunks = 8;
    while (nchunks > 1 &&
           (size_t)nchunks * E * (size_t)ntok * sizeof(float) > ws_size)
        nchunks >>= 1;
    const int dlen   = D / nchunks;
    const int ntiles = ntok / 256;

    float* partial = (float*)d_ws;

    hipLaunchKernelGGL(router_gemm, dim3(ntiles * nchunks), dim3(256), 0, stream,
                       x, W, partial, ntok, dlen, ntiles);
    hipLaunchKernelGGL(router_finish, dim3(ntok / 64), dim3(256), 0, stream,
                       partial, out, ntok, nchunks);
}

// Round 4
// 577.496 us; speedup vs baseline: 2.0435x; 2.0435x over previous
//
#include <hip/hip_runtime.h>
#include <math.h>

// TopExpertsRouter on MI355X (gfx950) — two-phase, bit-identical numerics to
// the PASSING rounds 1/3 (per-(token,expert): 8 chunks of sequential-512
// ascending fmaf chains, chunks summed ascending; identical softmax/top-k).
//
// Round-3 lesson: the compiler targets 8 waves/EU (64 VGPR) regardless of
// __launch_bounds__ min-waves, and restructures any >64-live-reg loop
// (acc[64] -> interchange, x re-read 64x, 33% VALUBusy). So: give each WAVE
// 16 experts (4 waves x 16 = 64), lane = token. acc[16] + x float4 ~= 48
// VGPRs -> fits the 64-VGPR target, no interchange incentive. W addresses
// are wave-uniform (readfirstlane base + constant offsets) -> scalar s_load
// on the scalar pipe; inner loop is 64 chained v_fmac_f32 per one x VMEM
// load. x rows are thread-private, consumed 16B-sequential (L1 absorbs the
// 4096-float lane stride).
//
// Round-1/3 finish lesson: 256 blocks = 1 block/CU = <=4 waves/CU -> pure
// latency-bound (~285us for 32MB). Now 1024 threads/block (16 waves/CU) and
// 32 independent outstanding loads/thread; reduction order still c-ascending
// (bit-equal), epilogue byte-identical.

constexpr int D = 4096;
constexpr int E = 64;
constexpr int K = 8;

__global__ __launch_bounds__(256) void router_gemm(
    const float* __restrict__ x, const float* __restrict__ W,
    float* __restrict__ partial, int ntok, int dlen, int ntiles)
{
    const int tid   = threadIdx.x;
    const int tile  = blockIdx.x % ntiles;   // 64-token tile
    const int chunk = blockIdx.x / ntiles;
    const int lane  = tid & 63;
    // wave-uniform expert base (0/16/32/48) -> SGPR, W loads become s_load
    const int e0 = __builtin_amdgcn_readfirstlane((tid >> 6) << 4);

    const int n  = tile * 64 + lane;
    const int d0 = chunk * dlen;

    float acc[16];
#pragma unroll
    for (int j = 0; j < 16; ++j) acc[j] = 0.f;

    const float* xp = x + (size_t)n * D + d0;
    const float* wp = W + (size_t)e0 * D + d0;   // SGPR base

#pragma unroll 2
    for (int d = 0; d < dlen; d += 4) {
        const float4 xv = *(const float4*)(xp + d);
#pragma unroll
        for (int j = 0; j < 16; ++j) {
            const float* w = wp + (size_t)j * D + d;  // SGPR base + const off
            float a = acc[j];
            a = fmaf(xv.x, w[0], a);
            a = fmaf(xv.y, w[1], a);
            a = fmaf(xv.z, w[2], a);
            a = fmaf(xv.w, w[3], a);
            acc[j] = a;
        }
    }

    // partial[chunk][e][token], lanes coalesced over token
    float* op = partial + ((size_t)chunk * E + e0) * ntok + n;
#pragma unroll
    for (int j = 0; j < 16; ++j) op[(size_t)j * ntok] = acc[j];
}

__global__ __launch_bounds__(1024) void router_finish(
    const float* __restrict__ partial, float* __restrict__ out,
    int ntok, int nchunks)
{
    __shared__ float ls[64][E + 4];   // stride 68

    const int tid = threadIdx.x;
    const int t0  = blockIdx.x * 64;
    const int t   = tid & 63;         // token lane (coalesced)
    const int eg  = tid >> 6;         // expert group 0..15

#pragma unroll
    for (int j = 0; j < 4; ++j) {
        const int e = eg * 4 + j;
        const float* p = partial + (size_t)e * ntok + t0 + t;
        float v = p[0];                              // chunk 0
        for (int c = 1; c < nchunks; ++c)            // ascending: bit-equal
            v += p[(size_t)c * E * ntok];
        ls[t][e] = v;
    }
    __syncthreads();

    if (tid < 64) {
        const int n = t0 + tid;
        float l[E];
#pragma unroll
        for (int g = 0; g < 16; ++g) {
            const float4 v = *(const float4*)&ls[tid][g * 4];
            l[g * 4 + 0] = v.x; l[g * 4 + 1] = v.y;
            l[g * 4 + 2] = v.z; l[g * 4 + 3] = v.w;
        }

        // ---- identical epilogue to rounds 1/3 ----
        float m = l[0];
#pragma unroll
        for (int e = 1; e < E; ++e) m = fmaxf(m, l[e]);
        float sum = 0.f;
#pragma unroll
        for (int e = 0; e < E; ++e) { l[e] = expf(l[e] - m); sum += l[e]; }
        const float inv = 1.f / sum;
#pragma unroll
        for (int e = 0; e < E; ++e) l[e] *= inv;

        float* probs = out + (size_t)ntok * 2 * K + (size_t)n * E;
#pragma unroll
        for (int g = 0; g < 16; ++g)
            *(float4*)&probs[g * 4] =
                make_float4(l[g * 4], l[g * 4 + 1], l[g * 4 + 2], l[g * 4 + 3]);

        float vals[K];
        int   idxs[K];
        float ts = 0.f;
        for (int k = 0; k < K; ++k) {
            float best = -1.f;
            int   bi   = 0;
#pragma unroll
            for (int e = 0; e < E; ++e)
                if (l[e] > best) { best = l[e]; bi = e; }
            vals[k] = best;
            idxs[k] = bi;
            ts += best;
#pragma unroll
            for (int e = 0; e < E; ++e)
                if (e == bi) l[e] = -1.f;
        }
        const float winv = 1.f / (ts + 1e-9f);

        float* oi = out + (size_t)n * K;
        float* ow = out + (size_t)ntok * K + (size_t)n * K;
#pragma unroll
        for (int k = 0; k < K; ++k) {
            oi[k] = (float)idxs[k];
            ow[k] = vals[k] * winv;
        }
    }
}

extern "C" void kernel_launch(void* const* d_in, const int* in_sizes, int n_in,
                              void* d_out, int out_size, void* d_ws, size_t ws_size,
                              hipStream_t stream)
{
    const float* x = (const float*)d_in[0];
    const float* W = (const float*)d_in[1];
    float* out = (float*)d_out;

    const int ntok = in_sizes[0] / D;  // 16384

    // identical nchunks policy to rounds 1/3 (bit-exactness anchor)
    int nchunks = 8;
    while (nchunks > 1 &&
           (size_t)nchunks * E * (size_t)ntok * sizeof(float) > ws_size)
        nchunks >>= 1;
    const int dlen   = D / nchunks;
    const int ntiles = ntok / 64;       // 64-token tiles

    float* partial = (float*)d_ws;

    hipLaunchKernelGGL(router_gemm, dim3(ntiles * nchunks), dim3(256), 0, stream,
                       x, W, partial, ntok, dlen, ntiles);
    hipLaunchKernelGGL(router_finish, dim3(ntok / 64), dim3(1024), 0, stream,
                       partial, out, ntok, nchunks);
}

// Round 5
// 526.215 us; speedup vs baseline: 2.2427x; 1.0975x over previous
//
#include <hip/hip_runtime.h>
#include <math.h>

// TopExpertsRouter on MI355X (gfx950) — two-phase, bit-identical numerics to
// PASSING rounds 1/3/4: per-(token,expert) logit = 8 chunks of ascending-512
// fmaf chains (xyzw within float4), chunks summed ascending; same epilogue.
//
// Round-4 lesson: a no-LDS kernel gets an 8-wave/EU, 64-VGPR budget and the
// allocator interchanges any accumulator array out of existence (VGPR=16!).
// An LDS-tiled kernel (34.8 KB -> 4 blocks/CU) gets a 128-VGPR budget and the
// classic 4x4 register tile survives. So phase 1 is the round-2 tiled GEMM
// (structure-only; its numerics bug is fixed by chunking):
//   block = (64-token tile) x (512-d chunk), 2048 blocks, 256 threads
//   per k-subtile (BK=64): stage x/W 16KB each -> 16 d4-steps of
//   8 ds_read_b128 (2-way bank alias = free) + 64 v_fmac_f32
//   expert map e = tx + 16j  (W-frag LDS rows stride 68*4B -> 2-way alias)
//   acc -> LDS (reuse xs) -> coalesced 256B partial stores [chunk][e][token]
// Phase 2: round-3 finish, chunk loop compile-time unrolled (16 independent
// 8-deep ascending load chains per thread), epilogue byte-identical.

constexpr int D  = 4096;
constexpr int E  = 64;
constexpr int K  = 8;
constexpr int BT = 64;   // tokens per block
constexpr int BK = 64;   // d sub-tile
constexpr int S  = 68;   // LDS row stride (floats)

__global__ __launch_bounds__(256) void router_gemm(
    const float* __restrict__ x, const float* __restrict__ W,
    float* __restrict__ partial, int ntok, int dlen, int ntiles)
{
    __shared__ float xs[BT][S];
    __shared__ float ws[E][S];

    const int tid   = threadIdx.x;
    const int tile  = blockIdx.x % ntiles;
    const int chunk = blockIdx.x / ntiles;
    const int t0 = tile * BT;
    const int d0 = chunk * dlen;

    // staging map: thread -> rows srow+16i, 4 cols at sc4*4 (256B/16-lane group)
    const int srow = tid >> 4;   // 0..15
    const int sc4  = tid & 15;   // 0..15
    const float* xg = x + (size_t)(t0 + srow) * D + d0 + sc4 * 4;
    const float* wg = W + (size_t)srow * D + d0 + sc4 * 4;

    // compute map: thread -> tokens ty*4+i, experts tx+16j
    const int tx = tid & 15;
    const int ty = tid >> 4;

    float acc[4][4];
#pragma unroll
    for (int i = 0; i < 4; ++i)
#pragma unroll
        for (int j = 0; j < 4; ++j) acc[i][j] = 0.f;

    const int nk = dlen / BK;
    for (int k = 0; k < nk; ++k) {
        float4 xr[4], wr[4];
#pragma unroll
        for (int i = 0; i < 4; ++i) {
            xr[i] = *(const float4*)(xg + k * BK + (size_t)16 * i * D);
            wr[i] = *(const float4*)(wg + k * BK + (size_t)16 * i * D);
        }
        __syncthreads();   // previous compute done before overwrite
#pragma unroll
        for (int i = 0; i < 4; ++i) {
            *(float4*)&xs[srow + 16 * i][sc4 * 4] = xr[i];
            *(float4*)&ws[srow + 16 * i][sc4 * 4] = wr[i];
        }
        __syncthreads();

#pragma unroll
        for (int d4 = 0; d4 < BK; d4 += 4) {
            float4 xf[4];
#pragma unroll
            for (int i = 0; i < 4; ++i)
                xf[i] = *(const float4*)&xs[ty * 4 + i][d4];
#pragma unroll
            for (int j = 0; j < 4; ++j) {
                const float4 wf = *(const float4*)&ws[tx + 16 * j][d4];
#pragma unroll
                for (int i = 0; i < 4; ++i) {
                    float a = acc[i][j];
                    a = fmaf(xf[i].x, wf.x, a);
                    a = fmaf(xf[i].y, wf.y, a);
                    a = fmaf(xf[i].z, wf.z, a);
                    a = fmaf(xf[i].w, wf.w, a);
                    acc[i][j] = a;
                }
            }
        }
    }

    // acc -> LDS (reuse xs as cs[e][token], stride S) -> coalesced stores
    __syncthreads();
    float (*cs)[S] = xs;
#pragma unroll
    for (int j = 0; j < 4; ++j)
#pragma unroll
        for (int i = 0; i < 4; ++i)
            cs[tx + 16 * j][ty * 4 + i] = acc[i][j];
    __syncthreads();

    const int w2 = tid >> 6;    // wave 0..3 -> experts w2*16..+15
    const int t  = tid & 63;
#pragma unroll
    for (int j = 0; j < 16; ++j) {
        const int e = w2 * 16 + j;
        partial[((size_t)chunk * E + e) * ntok + t0 + t] = cs[e][t];
    }
}

template <int NC>
__global__ __launch_bounds__(256) void router_finish(
    const float* __restrict__ partial, float* __restrict__ out, int ntok)
{
    __shared__ float ls[64][E + 4];

    const int tid = threadIdx.x;
    const int t0  = blockIdx.x * 64;
    const int t   = tid & 63;
    const int eg  = tid >> 6;

#pragma unroll
    for (int j = 0; j < 16; ++j) {
        const int e = eg * 16 + j;
        const float* p = partial + (size_t)e * ntok + t0 + t;
        float v = p[0];
#pragma unroll
        for (int c = 1; c < NC; ++c)            // ascending: bit-equal
            v += p[(size_t)c * E * ntok];
        ls[t][e] = v;
    }
    __syncthreads();

    if (tid < 64) {
        const int n = t0 + tid;
        float l[E];
#pragma unroll
        for (int g = 0; g < 16; ++g) {
            const float4 v = *(const float4*)&ls[tid][g * 4];
            l[g * 4 + 0] = v.x; l[g * 4 + 1] = v.y;
            l[g * 4 + 2] = v.z; l[g * 4 + 3] = v.w;
        }

        // ---- identical epilogue to rounds 1/3/4 ----
        float m = l[0];
#pragma unroll
        for (int e = 1; e < E; ++e) m = fmaxf(m, l[e]);
        float sum = 0.f;
#pragma unroll
        for (int e = 0; e < E; ++e) { l[e] = expf(l[e] - m); sum += l[e]; }
        const float inv = 1.f / sum;
#pragma unroll
        for (int e = 0; e < E; ++e) l[e] *= inv;

        float* probs = out + (size_t)ntok * 2 * K + (size_t)n * E;
#pragma unroll
        for (int g = 0; g < 16; ++g)
            *(float4*)&probs[g * 4] =
                make_float4(l[g * 4], l[g * 4 + 1], l[g * 4 + 2], l[g * 4 + 3]);

        float vals[K];
        int   idxs[K];
        float ts = 0.f;
        for (int k = 0; k < K; ++k) {
            float best = -1.f;
            int   bi   = 0;
#pragma unroll
            for (int e = 0; e < E; ++e)
                if (l[e] > best) { best = l[e]; bi = e; }
            vals[k] = best;
            idxs[k] = bi;
            ts += best;
#pragma unroll
            for (int e = 0; e < E; ++e)
                if (e == bi) l[e] = -1.f;
        }
        const float winv = 1.f / (ts + 1e-9f);

        float* oi = out + (size_t)n * K;
        float* ow = out + (size_t)ntok * K + (size_t)n * K;
#pragma unroll
        for (int k = 0; k < K; ++k) {
            oi[k] = (float)idxs[k];
            ow[k] = vals[k] * winv;
        }
    }
}

extern "C" void kernel_launch(void* const* d_in, const int* in_sizes, int n_in,
                              void* d_out, int out_size, void* d_ws, size_t ws_size,
                              hipStream_t stream)
{
    const float* x = (const float*)d_in[0];
    const float* W = (const float*)d_in[1];
    float* out = (float*)d_out;

    const int ntok = in_sizes[0] / D;  // 16384

    // identical nchunks policy to rounds 1/3/4 (bit-exactness anchor)
    int nchunks = 8;
    while (nchunks > 1 &&
           (size_t)nchunks * E * (size_t)ntok * sizeof(float) > ws_size)
        nchunks >>= 1;
    const int dlen   = D / nchunks;
    const int ntiles = ntok / BT;

    float* partial = (float*)d_ws;

    hipLaunchKernelGGL(router_gemm, dim3(ntiles * nchunks), dim3(256), 0, stream,
                       x, W, partial, ntok, dlen, ntiles);
    switch (nchunks) {
        case 8:
            hipLaunchKernelGGL(router_finish<8>, dim3(ntok / 64), dim3(256), 0,
                               stream, partial, out, ntok);
            break;
        case 4:
            hipLaunchKernelGGL(router_finish<4>, dim3(ntok / 64), dim3(256), 0,
                               stream, partial, out, ntok);
            break;
        case 2:
            hipLaunchKernelGGL(router_finish<2>, dim3(ntok / 64), dim3(256), 0,
                               stream, partial, out, ntok);
            break;
        default:
            hipLaunchKernelGGL(router_finish<1>, dim3(ntok / 64), dim3(256), 0,
                               stream, partial, out, ntok);
            break;
    }
}